// Round 5
// baseline (642.602 us; speedup 1.0000x reference)
//
#include <hip/hip_runtime.h>
#include <hip/hip_bf16.h>

// BiasedAxialAttention MI355X round 5: plane layouts for contiguous I/O.
//  q48/k48: [h][n][i][48]   (k_proj writes 12KB-contiguous tiles; k_qk BK=96 = 2 n-planes)
//  gate3/out3: [h][p][48]   (k_av LDS-repacked stores; k_out fused-gate plane staging)
//  k_out: fp32 stores repacked through LDS into 512B rows; 3 blocks/CU
//  k_av: mt-loop inside block (vT read from HBM once; attn is L2-resident)

#define LQ 384
#define DE 128
#define DBI 64
#define NH 4
#define DH 48
#define NPOS (LQ*LQ)     // 147456
#define KQK (LQ*DH)      // 18432

typedef __attribute__((ext_vector_type(8))) short short8;
typedef __attribute__((ext_vector_type(4))) float f32x4;
typedef unsigned short u16;
typedef unsigned int u32;

__device__ __forceinline__ float b2f(u16 u) {
  union { u32 i; float f; } v; v.i = ((u32)u) << 16; return v.f;
}
__device__ __forceinline__ u16 f2b(float f) {
  __hip_bfloat16 h = __float2bfloat16(f);
  return __builtin_bit_cast(unsigned short, h);
}
__device__ __forceinline__ float wred_sum(float v) {
  #pragma unroll
  for (int o = 32; o; o >>= 1) v += __shfl_down(v, o);
  return __shfl(v, 0);
}

// ---------------- 128x192 NT-GEMM mainloop, BK=64 (used by k_av)
__device__ __forceinline__ void gemm_128x192(
    const u16* __restrict__ A, long lda, const u16* __restrict__ B, long ldb,
    int kTiles, u16* sA, u16* sB, f32x4 (&acc)[4][6])
{
  const int t = threadIdx.x;
  const int w = t >> 6, lane = t & 63, quad = lane >> 4, l16 = lane & 15;
  const int wr = w >> 1, wc = w & 1;
  for (int kt = 0; kt < kTiles; ++kt) {
    #pragma unroll
    for (int r = 0; r < 4; ++r) {
      int id = t + r * 256, row = id >> 3, c8 = (id & 7) * 8;
      *(uint4*)(sA + row * 72 + c8) = *(const uint4*)(A + (long)row * lda + kt * 64 + c8);
    }
    #pragma unroll
    for (int r = 0; r < 6; ++r) {
      int id = t + r * 256, row = id >> 3, c8 = (id & 7) * 8;
      *(uint4*)(sB + row * 72 + c8) = *(const uint4*)(B + (long)row * ldb + kt * 64 + c8);
    }
    __syncthreads();
    #pragma unroll
    for (int kk = 0; kk < 64; kk += 32) {
      short8 a[4], bf[6];
      #pragma unroll
      for (int rr = 0; rr < 4; ++rr)
        a[rr] = *(const short8*)(sA + (wr * 64 + rr * 16 + l16) * 72 + kk + quad * 8);
      #pragma unroll
      for (int f = 0; f < 6; ++f)
        bf[f] = *(const short8*)(sB + (wc * 96 + f * 16 + l16) * 72 + kk + quad * 8);
      #pragma unroll
      for (int rr = 0; rr < 4; ++rr)
        #pragma unroll
        for (int f = 0; f < 6; ++f)
          acc[rr][f] = __builtin_amdgcn_mfma_f32_16x16x32_bf16(a[rr], bf[f], acc[rr][f], 0, 0, 0);
    }
    __syncthreads();
  }
}

// ---------------- kernel 0: weight transposes + RoPE tables
__global__ __launch_bounds__(256) void k_prep_w(
    const float* __restrict__ Wq, const float* __restrict__ Wk,
    const float* __restrict__ Wv, const float* __restrict__ Wg,
    const float* __restrict__ Wo, const int* __restrict__ epos,
    u16* __restrict__ WT, u16* __restrict__ WoT,
    float* __restrict__ cosT, float* __restrict__ sinT)
{
  int idx = blockIdx.x * 256 + threadIdx.x;
  if (idx < 768 * 128) {
    int col = idx >> 7, c = idx & 127;
    int which = col / 192, wi = col % 192;
    const float* W = (which == 0) ? Wq : (which == 1) ? Wk : (which == 2) ? Wv : Wg;
    WT[(long)col * 128 + c] = f2b(W[(long)c * 192 + wi]);
  }
  if (idx < 128 * 192) {
    int c = idx / 192, col = idx % 192;
    WoT[(long)c * 192 + col] = f2b(Wo[(long)col * 128 + c]);
  }
  if (idx < 384 * 24) {
    int i2 = idx / 24, dd = idx % 24;
    float ang = (float)epos[i2] * exp2f((float)dd * (-13.287712379549449f / 24.f));
    cosT[idx] = cosf(ang);
    sinT[idx] = sinf(ang);
  }
}

// ---------------- kernel 1: LN of transposed edge -> e_ln bf16 [p=n*384+i][128]
__global__ __launch_bounds__(256) void k_ln_e(
    const float* __restrict__ edge, const float* __restrict__ g,
    const float* __restrict__ b, u16* __restrict__ e_ln)
{
  int w = threadIdx.x >> 6, lane = threadIdx.x & 63;
  long p = (long)blockIdx.x * 4 + w;
  int n = (int)(p / LQ), i2 = (int)(p % LQ);
  const float* src = edge + ((long)i2 * LQ + n) * DE;   // transposed read
  float2 x = *(const float2*)(src + lane * 2);
  float mu = wred_sum(x.x + x.y) * (1.f / 128.f);
  float ms = wred_sum(x.x * x.x + x.y * x.y) * (1.f / 128.f);
  float r = rsqrtf(ms - mu * mu + 1e-5f);
  int c = lane * 2;
  u16 y0 = f2b((x.x - mu) * r * g[c] + b[c]);
  u16 y1 = f2b((x.y - mu) * r * g[c + 1] + b[c + 1]);
  *(u32*)(e_ln + p * DE + c) = (u32)y0 | ((u32)y1 << 16);
}

// ---------------- kernel 2: LN(bias^T) @ Wb -> bh  [h][i][j]
__global__ __launch_bounds__(256) void k_bias(
    const float* __restrict__ bias, const float* __restrict__ g,
    const float* __restrict__ b, const float* __restrict__ Wb,
    float* __restrict__ bh)
{
  int w = threadIdx.x >> 6, lane = threadIdx.x & 63;
  long q = (long)blockIdx.x * 4 + w;
  int i = (int)(q / LQ), j = (int)(q % LQ);
  float x = bias[((long)j * LQ + i) * DBI + lane];       // transposed read
  float mu = wred_sum(x) * (1.f / 64.f);
  float ms = wred_sum(x * x) * (1.f / 64.f);
  float r = rsqrtf(ms - mu * mu + 1e-5f);
  float y = (x - mu) * r * g[lane] + b[lane];
  #pragma unroll
  for (int h = 0; h < 4; ++h) {
    float v = y * Wb[lane * 4 + h];
    #pragma unroll
    for (int o = 32; o; o >>= 1) v += __shfl_down(v, o);
    if (lane == 0) bh[((long)h * LQ + i) * LQ + j] = v;
  }
}

// ---------------- kernel 3: projections, A-resident, plane-layout outputs. grid(1152)
__global__ __launch_bounds__(256) void k_proj(
    const u16* __restrict__ e_ln, const u16* __restrict__ WT,
    const float* __restrict__ cosT, const float* __restrict__ sinT,
    const float* __restrict__ bg,
    u16* __restrict__ q48, u16* __restrict__ k48,
    u16* __restrict__ vT, u16* __restrict__ gate3)
{
  __shared__ __align__(16) u16 sA[128 * 136];     // 34816 B
  __shared__ __align__(16) u16 sB[48 * 136];      // 13056 B
  __shared__ __align__(16) float sC[128 * 49];    // 25088 B  (total 72960 -> 2/CU)
  const int t = threadIdx.x;
  const int w = t >> 6, lane = t & 63, quad = lane >> 4, l16 = lane & 15;
  long mt = blockIdx.x;
  long pbase = mt * 128;
  int n = (int)(pbase / LQ), i2base = (int)(pbase % LQ);

  // stage A once: 128 rows x 128 K
  #pragma unroll
  for (int r = 0; r < 8; ++r) {
    int id = t + r * 256, row = id >> 4, c8 = (id & 15) * 8;
    *(uint4*)(sA + row * 136 + c8) = *(const uint4*)(e_ln + (pbase + row) * DE + c8);
  }
  __syncthreads();
  short8 a[2][4];
  #pragma unroll
  for (int rr = 0; rr < 2; ++rr)
    #pragma unroll
    for (int kki = 0; kki < 4; ++kki)
      a[rr][kki] = *(const short8*)(sA + (w * 32 + rr * 16 + l16) * 136 + kki * 32 + quad * 8);

  for (int cc = 0; cc < 16; ++cc) {
    int which = cc >> 2, h = cc & 3;
    #pragma unroll
    for (int r = 0; r < 3; ++r) {
      int id = t + r * 256, row = id >> 4, c8 = (id & 15) * 8;
      *(uint4*)(sB + row * 136 + c8) = *(const uint4*)(WT + ((long)cc * 48 + row) * DE + c8);
    }
    __syncthreads();   // sync1: sB ready; prev epilogue done reading sC
    f32x4 acc[2][3] = {};
    #pragma unroll
    for (int kki = 0; kki < 4; ++kki)
      #pragma unroll
      for (int f = 0; f < 3; ++f) {
        short8 bf = *(const short8*)(sB + (f * 16 + l16) * 136 + kki * 32 + quad * 8);
        acc[0][f] = __builtin_amdgcn_mfma_f32_16x16x32_bf16(a[0][kki], bf, acc[0][f], 0, 0, 0);
        acc[1][f] = __builtin_amdgcn_mfma_f32_16x16x32_bf16(a[1][kki], bf, acc[1][f], 0, 0, 0);
      }
    #pragma unroll
    for (int rr = 0; rr < 2; ++rr)
      #pragma unroll
      for (int f = 0; f < 3; ++f)
        #pragma unroll
        for (int r = 0; r < 4; ++r)
          sC[(w * 32 + rr * 16 + quad * 4 + r) * 49 + f * 16 + l16] = acc[rr][f][r];
    __syncthreads();   // sync2: sC ready

    if (which < 2) {
      // q/k plane [h][n][i][48]: contiguous 12KB block per phase
      float scl = (which == 0) ? 0.14433756729740643f : (1.0f / 384.0f);
      u16* base = ((which == 0) ? q48 : k48) + ((long)(h * LQ + n) * LQ + i2base) * DH;
      #pragma unroll
      for (int it = 0; it < 3; ++it) {
        int id = t + it * 256;
        int row = id / 6, c8 = (id % 6) * 8;
        int i2 = i2base + row;
        const float* ct = cosT + i2 * 24;
        const float* st = sinT + i2 * 24;
        union { u16 s[8]; uint4 v; } o;
        #pragma unroll
        for (int u = 0; u < 8; ++u) {
          int d = c8 + u;
          int dd = (d < 24) ? d : d - 24;
          float x1 = sC[row * 49 + dd], x2 = sC[row * 49 + dd + 24];
          float y = (d < 24) ? (x1 * ct[dd] - x2 * st[dd]) : (x1 * st[dd] + x2 * ct[dd]);
          o.s[u] = f2b(y * scl);
        }
        *(uint4*)(base + (long)row * DH + c8) = o.v;
      }
    } else if (which == 2) {
      // vT[h][n*48+d][j]: packed along j
      #pragma unroll
      for (int it = 0; it < 3; ++it) {
        int id = t + it * 256;
        int d = id >> 4, j8 = (id & 15) * 8;
        union { u16 s[8]; uint4 v; } o;
        #pragma unroll
        for (int u = 0; u < 8; ++u) o.s[u] = f2b(sC[(j8 + u) * 49 + d]);
        *(uint4*)(vT + ((long)h * KQK + n * DH + d) * LQ + i2base + j8) = o.v;
      }
    } else {
      // gate3 plane [h][p][48]: contiguous
      #pragma unroll
      for (int it = 0; it < 3; ++it) {
        int id = t + it * 256;
        int row = id / 6, c8 = (id % 6) * 8;
        union { u16 s[8]; uint4 v; } o;
        #pragma unroll
        for (int u = 0; u < 8; ++u) {
          int d = c8 + u;
          float xx = sC[row * 49 + d] + bg[h * DH + d];
          o.s[u] = f2b(1.f / (1.f + __expf(-xx)));
        }
        *(uint4*)(gate3 + ((long)h * NPOS + pbase + row) * DH + c8) = o.v;
      }
    }
    // no trailing barrier: next phase's sync1 protects sC
  }
}

// ---------------- kernel 4: partial[s] = Q K^T slice, plane BK=96 (2 n-planes/kt)
// grid x = s*2+nt (32), y = mt(3), z = h(4); s covers 24 n-planes (12 kt)
__global__ __launch_bounds__(256) void k_qk(
    const u16* __restrict__ q48, const u16* __restrict__ k48,
    float* __restrict__ partial)
{
  __shared__ __align__(16) u16 sA[128 * 104];   // 26624 B
  __shared__ __align__(16) u16 sB[192 * 104];   // 39936 B  (total 66560 -> 2/CU)
  int nt = blockIdx.x & 1, s = blockIdx.x >> 1;
  int mt = blockIdx.y, h = blockIdx.z;
  const int t = threadIdx.x;
  const int w = t >> 6, lane = t & 63, quad = lane >> 4, l16 = lane & 15;
  const int wr = w >> 1, wc = w & 1;
  f32x4 acc[4][6] = {};
  for (int kt = 0; kt < 12; ++kt) {
    int n0 = s * 24 + kt * 2;
    #pragma unroll
    for (int r = 0; r < 6; ++r) {           // A: 128 rows x 96 (2 planes x 48)
      int p = r / 3;
      int rem = t + (r - p * 3) * 256;
      int row = rem / 6, c8 = (rem % 6) * 8;
      *(uint4*)(sA + row * 104 + p * 48 + c8) =
        *(const uint4*)(q48 + (((long)h * LQ + n0 + p) * LQ + mt * 128 + row) * DH + c8);
    }
    #pragma unroll
    for (int r = 0; r < 9; ++r) {           // B: 192 rows x 96
      int id = t + r * 256;
      int p = (id >= 1152) ? 1 : 0;
      int rem = id - p * 1152;
      int row = rem / 6, c8 = (rem % 6) * 8;
      *(uint4*)(sB + row * 104 + p * 48 + c8) =
        *(const uint4*)(k48 + (((long)h * LQ + n0 + p) * LQ + nt * 192 + row) * DH + c8);
    }
    __syncthreads();
    #pragma unroll
    for (int kk = 0; kk < 96; kk += 32) {
      short8 a[4], bf[6];
      #pragma unroll
      for (int rr = 0; rr < 4; ++rr)
        a[rr] = *(const short8*)(sA + (wr * 64 + rr * 16 + l16) * 104 + kk + quad * 8);
      #pragma unroll
      for (int f = 0; f < 6; ++f)
        bf[f] = *(const short8*)(sB + (wc * 96 + f * 16 + l16) * 104 + kk + quad * 8);
      #pragma unroll
      for (int rr = 0; rr < 4; ++rr)
        #pragma unroll
        for (int f = 0; f < 6; ++f)
          acc[rr][f] = __builtin_amdgcn_mfma_f32_16x16x32_bf16(a[rr], bf[f], acc[rr][f], 0, 0, 0);
    }
    __syncthreads();
  }
  float* dst = partial + ((long)s * NH + h) * NPOS;
  #pragma unroll
  for (int rr = 0; rr < 4; ++rr)
    #pragma unroll
    for (int f = 0; f < 6; ++f)
      #pragma unroll
      for (int r = 0; r < 4; ++r) {
        int row = mt * 128 + wr * 64 + rr * 16 + quad * 4 + r;
        int col = nt * 192 + wc * 96 + f * 16 + l16;
        dst[(long)row * LQ + col] = acc[rr][f][r];
      }
}

// ---------------- kernel 5: reduce 16 partials + bh, softmax over j, mask -> attn
__global__ __launch_bounds__(256) void k_softmax(
    const float* __restrict__ partial, const float* __restrict__ bh,
    const float* __restrict__ mask, u16* __restrict__ attn)
{
  int w = threadIdx.x >> 6, lane = threadIdx.x & 63;
  long row = (long)blockIdx.x * 4 + w;   // row = h*384 + i
  int i = (int)(row % LQ);
  float v[6];
  #pragma unroll
  for (int j0 = 0; j0 < 6; ++j0) v[j0] = bh[row * LQ + lane + j0 * 64];
  for (int s = 0; s < 16; ++s) {
    const float* p = partial + (long)s * NH * NPOS + row * LQ;
    #pragma unroll
    for (int j0 = 0; j0 < 6; ++j0) v[j0] += p[lane + j0 * 64];
  }
  float mx = -1e30f;
  #pragma unroll
  for (int j0 = 0; j0 < 6; ++j0) mx = fmaxf(mx, v[j0]);
  #pragma unroll
  for (int o = 32; o; o >>= 1) mx = fmaxf(mx, __shfl_down(mx, o));
  mx = __shfl(mx, 0);
  float sum = 0.f;
  #pragma unroll
  for (int j0 = 0; j0 < 6; ++j0) { v[j0] = __expf(v[j0] - mx); sum += v[j0]; }
  sum = wred_sum(sum);
  float inv = 1.f / sum;
  #pragma unroll
  for (int j0 = 0; j0 < 6; ++j0) {
    int j = lane + j0 * 64;
    float p = v[j0] * inv + 1.0e6f * (mask[(long)i * LQ + j] - 1.f);
    attn[row * LQ + j] = f2b(p);
  }
}

// ---------------- kernel 6: out3[h][p][48] = attn @ vT^T, mt-loop inside. grid (96, 4)
__global__ __launch_bounds__(256) void k_av(
    const u16* __restrict__ attn, const u16* __restrict__ vT,
    u16* __restrict__ out3)
{
  __shared__ __align__(16) u16 sA[128 * 72];    // 18432 B
  __shared__ __align__(16) u16 sB[192 * 72];    // 27648 B (total 46080 -> 3/CU)
  int nt = blockIdx.x, h = blockIdx.y;
  const int t = threadIdx.x;
  const int w = t >> 6, lane = t & 63, quad = lane >> 4, l16 = lane & 15;
  const int wr = w >> 1, wc = w & 1;
  for (int mt = 0; mt < 3; ++mt) {
    f32x4 acc[4][6] = {};
    gemm_128x192(attn + ((long)h * LQ + mt * 128) * LQ, LQ,
                 vT + ((long)h * KQK + nt * 192) * LQ, LQ,
                 6, sA, sB, acc);
    // repack C (128 x 192) -> out3 contiguous, via sB in 2 chunks of 96 cols
    u16* sCb = sB;
    #pragma unroll
    for (int ch = 0; ch < 2; ++ch) {
      if (wc == ch) {
        #pragma unroll
        for (int rr = 0; rr < 4; ++rr)
          #pragma unroll
          for (int f = 0; f < 6; ++f)
            #pragma unroll
            for (int r = 0; r < 4; ++r)
              sCb[(wr * 64 + rr * 16 + quad * 4 + r) * 104 + f * 16 + l16] = f2b(acc[rr][f][r]);
      }
      __syncthreads();
      #pragma unroll
      for (int r2 = 0; r2 < 6; ++r2) {
        int id = t + r2 * 256;          // 128*96/8 = 1536 uint4
        int row = id / 12, u = id % 12;
        int nnl = u / 6, c8 = (u % 6) * 8;
        int nval = nt * 4 + ch * 2 + nnl;
        *(uint4*)(out3 + ((long)h * NPOS + (long)nval * LQ + mt * 128 + row) * DH + c8) =
          *(const uint4*)(sCb + row * 104 + nnl * 48 + c8);
      }
      __syncthreads();
    }
  }
}

// ---------------- kernel 7: final = (out3 .* gate3) @ Wo, plane BK=96, repacked fp32 stores
__global__ __launch_bounds__(256) void k_out(
    const u16* __restrict__ out3, const u16* __restrict__ gate3,
    const u16* __restrict__ WoT, float* __restrict__ outp)
{
  __shared__ __align__(16) u16 sA[128 * 104];   // 26624 B
  __shared__ __align__(16) u16 sB[128 * 104];   // 26624 B (total 53248 -> 3/CU)
  long mt = blockIdx.x;
  long pbase = mt * 128;
  const int t = threadIdx.x;
  const int w = t >> 6, lane = t & 63, quad = lane >> 4, l16 = lane & 15;
  const int wr = w >> 1, wc = w & 1;
  f32x4 acc[4][4] = {};
  for (int kt = 0; kt < 2; ++kt) {
    #pragma unroll
    for (int r = 0; r < 6; ++r) {      // A: 128 x 96 = planes (kt*2, kt*2+1), gate fused
      int p = r / 3;
      int rem = t + (r - p * 3) * 256;
      int row = rem / 6, c8 = (rem % 6) * 8;
      long off = ((long)(kt * 2 + p) * NPOS + pbase + row) * DH + c8;
      union { u16 s[8]; uint4 v; } ua, ub, ur;
      ua.v = *(const uint4*)(out3 + off);
      ub.v = *(const uint4*)(gate3 + off);
      #pragma unroll
      for (int q2 = 0; q2 < 8; ++q2) ur.s[q2] = f2b(b2f(ua.s[q2]) * b2f(ub.s[q2]));
      *(uint4*)(sA + row * 104 + p * 48 + c8) = ur.v;
    }
    #pragma unroll
    for (int r = 0; r < 6; ++r) {      // B: 128 rows(c) x 96 K
      int p = r / 3;
      int rem = t + (r - p * 3) * 256;
      int row = rem / 6, c8 = (rem % 6) * 8;
      *(uint4*)(sB + row * 104 + p * 48 + c8) =
        *(const uint4*)(WoT + (long)row * 192 + kt * 96 + p * 48 + c8);
    }
    __syncthreads();
    #pragma unroll
    for (int kk = 0; kk < 96; kk += 32) {
      short8 a[4], bf[4];
      #pragma unroll
      for (int rr = 0; rr < 4; ++rr)
        a[rr] = *(const short8*)(sA + (wr * 64 + rr * 16 + l16) * 104 + kk + quad * 8);
      #pragma unroll
      for (int f = 0; f < 4; ++f)
        bf[f] = *(const short8*)(sB + (wc * 64 + f * 16 + l16) * 104 + kk + quad * 8);
      #pragma unroll
      for (int rr = 0; rr < 4; ++rr)
        #pragma unroll
        for (int f = 0; f < 4; ++f)
          acc[rr][f] = __builtin_amdgcn_mfma_f32_16x16x32_bf16(a[rr], bf[f], acc[rr][f], 0, 0, 0);
    }
    __syncthreads();
  }
  int n = (int)(pbase / LQ), ibase = (int)(pbase % LQ);
  float* sAf = (float*)sA;   // 32 x 132 fp32 = 16896 B chunk buffer
  #pragma unroll
  for (int pass = 0; pass < 4; ++pass) {
    if (wr == (pass >> 1)) {
      #pragma unroll
      for (int rr2 = 0; rr2 < 2; ++rr2) {
        int rr = (pass & 1) * 2 + rr2;
        #pragma unroll
        for (int f = 0; f < 4; ++f)
          #pragma unroll
          for (int r = 0; r < 4; ++r)
            sAf[(rr2 * 16 + quad * 4 + r) * 132 + wc * 64 + f * 16 + l16] = acc[rr][f][r];
      }
    }
    __syncthreads();
    #pragma unroll
    for (int r2 = 0; r2 < 4; ++r2) {
      int id = t + r2 * 256;           // 32*128/4 = 1024 float4
      int row32 = id >> 5, c4 = id & 31;
      float4 v = *(const float4*)(sAf + row32 * 132 + c4 * 4);
      *(float4*)(outp + ((long)(ibase + pass * 32 + row32) * LQ + n) * DE + c4 * 4) = v;
    }
    __syncthreads();
  }
}

extern "C" void kernel_launch(void* const* d_in, const int* in_sizes, int n_in,
                              void* d_out, int out_size, void* d_ws, size_t ws_size,
                              hipStream_t stream)
{
  const float* edge   = (const float*)d_in[0];
  const float* bias   = (const float*)d_in[1];
  const int*   epos   = (const int*)d_in[2];
  const float* mask   = (const float*)d_in[3];
  const float* ln_e_g = (const float*)d_in[4];
  const float* ln_e_b = (const float*)d_in[5];
  const float* ln_b_g = (const float*)d_in[6];
  const float* ln_b_b = (const float*)d_in[7];
  const float* Wq = (const float*)d_in[8];
  const float* Wk = (const float*)d_in[9];
  const float* Wv = (const float*)d_in[10];
  const float* Wb = (const float*)d_in[11];
  const float* Wg = (const float*)d_in[12];
  const float* bg = (const float*)d_in[13];
  const float* Wo = (const float*)d_in[14];
  float* outp = (float*)d_out;

  char* ws = (char*)d_ws;
  const size_t SZ = (size_t)NPOS * 192 * 2;   // 56,623,104 B
  // slot0 timeline: e_ln (k_ln_e->k_proj) -> partial (k_qk->k_softmax) -> out3 (k_av->k_out)
  u16* e_ln      = (u16*)ws;                  // 37.7 MB
  float* partial = (float*)ws;                // 16 x 2.36 MB = 37.7 MB
  u16* out3      = (u16*)ws;                  // [4][147456][48] = 56.6 MB
  u16* q48   = (u16*)(ws + SZ);               // [4][384][384][48]
  u16* k48   = (u16*)(ws + 2 * SZ);
  u16* vTb   = (u16*)(ws + 3 * SZ);
  u16* gate3 = (u16*)(ws + 4 * SZ);           // [4][147456][48]
  float* bh  = (float*)(ws + 5 * SZ);         // [4][384][384] fp32
  u16* attn  = (u16*)(ws + 5 * SZ + 2359296);
  u16* WT    = (u16*)(ws + 5 * SZ + 2359296 + 1179648);
  u16* WoT   = (u16*)(ws + 5 * SZ + 2359296 + 1179648 + 196608);
  float* cosT = (float*)(ws + 5 * SZ + 2359296 + 1179648 + 196608 + 49152);
  float* sinT = cosT + 384 * 24;

  k_prep_w<<<dim3(384), dim3(256), 0, stream>>>(Wq, Wk, Wv, Wg, Wo, epos, WT, WoT, cosT, sinT);
  k_bias<<<dim3(36864), dim3(256), 0, stream>>>(bias, ln_b_g, ln_b_b, Wb, bh);
  k_ln_e<<<dim3(36864), dim3(256), 0, stream>>>(edge, ln_e_g, ln_e_b, e_ln);
  k_proj<<<dim3(1152), dim3(256), 0, stream>>>(e_ln, WT, cosT, sinT, bg,
                                               q48, k48, vTb, gate3);
  k_qk<<<dim3(32, 3, 4), dim3(256), 0, stream>>>(q48, k48, partial);
  k_softmax<<<dim3(384), dim3(256), 0, stream>>>(partial, bh, mask, attn);
  k_av<<<dim3(96, 4), dim3(256), 0, stream>>>(attn, vTb, out3);
  k_out<<<dim3(1152), dim3(256), 0, stream>>>(out3, gate3, WoT, outp);
}

// Round 6
// 579.025 us; speedup vs baseline: 1.1098x; 1.1098x over previous
//
#include <hip/hip_runtime.h>
#include <hip/hip_bf16.h>

// BiasedAxialAttention MI355X round 6: barrier-free k_proj.
//  - k_proj: A/B fragments global->register (no LDS staging, no __syncthreads at all);
//    C repack via per-wave LDS slices + lgkmcnt-only fences; RoPE via dual-half readback.
//  - k_av/k_out: per-wave fence-based repack (stores never drained by an immediate barrier).

#define LQ 384
#define DE 128
#define DBI 64
#define NH 4
#define DH 48
#define NPOS (LQ*LQ)     // 147456
#define KQK (LQ*DH)      // 18432

typedef __attribute__((ext_vector_type(8))) short short8;
typedef __attribute__((ext_vector_type(4))) float f32x4;
typedef unsigned short u16;
typedef unsigned int u32;

#define LFENCE() asm volatile("s_waitcnt lgkmcnt(0)" ::: "memory")

__device__ __forceinline__ float b2f(u16 u) {
  union { u32 i; float f; } v; v.i = ((u32)u) << 16; return v.f;
}
__device__ __forceinline__ u16 f2b(float f) {
  __hip_bfloat16 h = __float2bfloat16(f);
  return __builtin_bit_cast(unsigned short, h);
}
__device__ __forceinline__ float wred_sum(float v) {
  #pragma unroll
  for (int o = 32; o; o >>= 1) v += __shfl_down(v, o);
  return __shfl(v, 0);
}

// ---------------- 128x192 NT-GEMM mainloop, BK=64 (used by k_av)
__device__ __forceinline__ void gemm_128x192(
    const u16* __restrict__ A, long lda, const u16* __restrict__ B, long ldb,
    int kTiles, u16* sA, u16* sB, f32x4 (&acc)[4][6])
{
  const int t = threadIdx.x;
  const int w = t >> 6, lane = t & 63, quad = lane >> 4, l16 = lane & 15;
  const int wr = w >> 1, wc = w & 1;
  for (int kt = 0; kt < kTiles; ++kt) {
    #pragma unroll
    for (int r = 0; r < 4; ++r) {
      int id = t + r * 256, row = id >> 3, c8 = (id & 7) * 8;
      *(uint4*)(sA + row * 72 + c8) = *(const uint4*)(A + (long)row * lda + kt * 64 + c8);
    }
    #pragma unroll
    for (int r = 0; r < 6; ++r) {
      int id = t + r * 256, row = id >> 3, c8 = (id & 7) * 8;
      *(uint4*)(sB + row * 72 + c8) = *(const uint4*)(B + (long)row * ldb + kt * 64 + c8);
    }
    __syncthreads();
    #pragma unroll
    for (int kk = 0; kk < 64; kk += 32) {
      short8 a[4], bf[6];
      #pragma unroll
      for (int rr = 0; rr < 4; ++rr)
        a[rr] = *(const short8*)(sA + (wr * 64 + rr * 16 + l16) * 72 + kk + quad * 8);
      #pragma unroll
      for (int f = 0; f < 6; ++f)
        bf[f] = *(const short8*)(sB + (wc * 96 + f * 16 + l16) * 72 + kk + quad * 8);
      #pragma unroll
      for (int rr = 0; rr < 4; ++rr)
        #pragma unroll
        for (int f = 0; f < 6; ++f)
          acc[rr][f] = __builtin_amdgcn_mfma_f32_16x16x32_bf16(a[rr], bf[f], acc[rr][f], 0, 0, 0);
    }
    __syncthreads();
  }
}

// ---------------- kernel 0: weight transposes + RoPE tables
__global__ __launch_bounds__(256) void k_prep_w(
    const float* __restrict__ Wq, const float* __restrict__ Wk,
    const float* __restrict__ Wv, const float* __restrict__ Wg,
    const float* __restrict__ Wo, const int* __restrict__ epos,
    u16* __restrict__ WT, u16* __restrict__ WoT,
    float* __restrict__ cosT, float* __restrict__ sinT)
{
  int idx = blockIdx.x * 256 + threadIdx.x;
  if (idx < 768 * 128) {
    int col = idx >> 7, c = idx & 127;
    int which = col / 192, wi = col % 192;
    const float* W = (which == 0) ? Wq : (which == 1) ? Wk : (which == 2) ? Wv : Wg;
    WT[(long)col * 128 + c] = f2b(W[(long)c * 192 + wi]);
  }
  if (idx < 128 * 192) {
    int c = idx / 192, col = idx % 192;
    WoT[(long)c * 192 + col] = f2b(Wo[(long)col * 128 + c]);
  }
  if (idx < 384 * 24) {
    int i2 = idx / 24, dd = idx % 24;
    float ang = (float)epos[i2] * exp2f((float)dd * (-13.287712379549449f / 24.f));
    cosT[idx] = cosf(ang);
    sinT[idx] = sinf(ang);
  }
}

// ---------------- kernel 1: LN of transposed edge -> e_ln bf16 [p=n*384+i][128]
__global__ __launch_bounds__(256) void k_ln_e(
    const float* __restrict__ edge, const float* __restrict__ g,
    const float* __restrict__ b, u16* __restrict__ e_ln)
{
  int w = threadIdx.x >> 6, lane = threadIdx.x & 63;
  long p = (long)blockIdx.x * 4 + w;
  int n = (int)(p / LQ), i2 = (int)(p % LQ);
  const float* src = edge + ((long)i2 * LQ + n) * DE;   // transposed read
  float2 x = *(const float2*)(src + lane * 2);
  float mu = wred_sum(x.x + x.y) * (1.f / 128.f);
  float ms = wred_sum(x.x * x.x + x.y * x.y) * (1.f / 128.f);
  float r = rsqrtf(ms - mu * mu + 1e-5f);
  int c = lane * 2;
  u16 y0 = f2b((x.x - mu) * r * g[c] + b[c]);
  u16 y1 = f2b((x.y - mu) * r * g[c + 1] + b[c + 1]);
  *(u32*)(e_ln + p * DE + c) = (u32)y0 | ((u32)y1 << 16);
}

// ---------------- kernel 2: LN(bias^T) @ Wb -> bh  [h][i][j]
__global__ __launch_bounds__(256) void k_bias(
    const float* __restrict__ bias, const float* __restrict__ g,
    const float* __restrict__ b, const float* __restrict__ Wb,
    float* __restrict__ bh)
{
  int w = threadIdx.x >> 6, lane = threadIdx.x & 63;
  long q = (long)blockIdx.x * 4 + w;
  int i = (int)(q / LQ), j = (int)(q % LQ);
  float x = bias[((long)j * LQ + i) * DBI + lane];       // transposed read
  float mu = wred_sum(x) * (1.f / 64.f);
  float ms = wred_sum(x * x) * (1.f / 64.f);
  float r = rsqrtf(ms - mu * mu + 1e-5f);
  float y = (x - mu) * r * g[lane] + b[lane];
  #pragma unroll
  for (int h = 0; h < 4; ++h) {
    float v = y * Wb[lane * 4 + h];
    #pragma unroll
    for (int o = 32; o; o >>= 1) v += __shfl_down(v, o);
    if (lane == 0) bh[((long)h * LQ + i) * LQ + j] = v;
  }
}

// ---------------- kernel 3: projections, barrier-free. grid (1152)
// A,B fragments global->register; per-wave LDS repack (lgkm fences only).
__global__ __launch_bounds__(256) void k_proj(
    const u16* __restrict__ e_ln, const u16* __restrict__ WT,
    const float* __restrict__ cosT, const float* __restrict__ sinT,
    const float* __restrict__ bg,
    u16* __restrict__ q48, u16* __restrict__ k48,
    u16* __restrict__ vT, u16* __restrict__ gate3)
{
  __shared__ __align__(16) char sR[4][7936];   // per-wave repack slices (31 KB)
  const int t = threadIdx.x;
  const int w = t >> 6, lane = t & 63, quad = lane >> 4, l16 = lane & 15;
  long mt = blockIdx.x;
  long pbase = mt * 128;
  int n = (int)(pbase / LQ), i2base = (int)(pbase % LQ);

  // A fragments direct from global (tile read exactly once by its block)
  short8 a[2][4];
  #pragma unroll
  for (int rr = 0; rr < 2; ++rr)
    #pragma unroll
    for (int kki = 0; kki < 4; ++kki)
      a[rr][kki] = *(const short8*)(e_ln + (pbase + w * 32 + rr * 16 + l16) * DE + kki * 32 + quad * 8);

  const int row = lane >> 1, half = lane & 1;   // repack readback mapping
  const int i2 = i2base + w * 32 + row;
  char* R = sR[w];

  for (int cc = 0; cc < 16; ++cc) {
    int which = cc >> 2, h = cc & 3;
    // B fragments direct from global (WT is L2/L1-resident)
    short8 b[3][4];
    #pragma unroll
    for (int f = 0; f < 3; ++f)
      #pragma unroll
      for (int kki = 0; kki < 4; ++kki)
        b[f][kki] = *(const short8*)(WT + ((long)cc * 48 + f * 16 + l16) * DE + kki * 32 + quad * 8);
    f32x4 acc[2][3] = {};
    #pragma unroll
    for (int kki = 0; kki < 4; ++kki)
      #pragma unroll
      for (int f = 0; f < 3; ++f) {
        acc[0][f] = __builtin_amdgcn_mfma_f32_16x16x32_bf16(a[0][kki], b[f][kki], acc[0][f], 0, 0, 0);
        acc[1][f] = __builtin_amdgcn_mfma_f32_16x16x32_bf16(a[1][kki], b[f][kki], acc[1][f], 0, 0, 0);
      }
    LFENCE();   // previous phase's slice reads complete before overwrite

    if (which < 2) {
      // q/k: fp32 C into slice (stride 60 f32), dual-half readback, RoPE, packed store
      float* Rf = (float*)R;
      #pragma unroll
      for (int rr = 0; rr < 2; ++rr)
        #pragma unroll
        for (int f = 0; f < 3; ++f)
          #pragma unroll
          for (int r = 0; r < 4; ++r)
            Rf[(rr * 16 + quad * 4 + r) * 60 + f * 16 + l16] = acc[rr][f][r];
      LFENCE();
      float own[24], oth[24], cs[24], sn[24];
      #pragma unroll
      for (int e4 = 0; e4 < 6; ++e4) {
        float4 v1 = *(const float4*)(Rf + row * 60 + half * 24 + e4 * 4);
        float4 v2 = *(const float4*)(Rf + row * 60 + (1 - half) * 24 + e4 * 4);
        float4 c1 = *(const float4*)(cosT + i2 * 24 + e4 * 4);
        float4 s1 = *(const float4*)(sinT + i2 * 24 + e4 * 4);
        own[e4*4+0]=v1.x; own[e4*4+1]=v1.y; own[e4*4+2]=v1.z; own[e4*4+3]=v1.w;
        oth[e4*4+0]=v2.x; oth[e4*4+1]=v2.y; oth[e4*4+2]=v2.z; oth[e4*4+3]=v2.w;
        cs[e4*4+0]=c1.x; cs[e4*4+1]=c1.y; cs[e4*4+2]=c1.z; cs[e4*4+3]=c1.w;
        sn[e4*4+0]=s1.x; sn[e4*4+1]=s1.y; sn[e4*4+2]=s1.z; sn[e4*4+3]=s1.w;
      }
      float scl = (which == 0) ? 0.14433756729740643f : (1.0f / 384.0f);
      float sgn = half ? 1.f : -1.f;
      u16* dst = ((which == 0) ? q48 : k48) + ((long)(h * LQ + n) * LQ + i2) * 48 + half * 24;
      #pragma unroll
      for (int v3 = 0; v3 < 3; ++v3) {
        union { u16 s[8]; uint4 q; } o;
        #pragma unroll
        for (int j = 0; j < 8; ++j) {
          int e = v3 * 8 + j;
          o.s[j] = f2b((own[e] * cs[e] + sgn * oth[e] * sn[e]) * scl);
        }
        *(uint4*)(dst + v3 * 8) = o.q;
      }
    } else if (which == 2) {
      // v: transposed bf16 into slice (addr = d*40 + j), contiguous-ish readout
      u16* Ru = (u16*)R;
      #pragma unroll
      for (int rr = 0; rr < 2; ++rr)
        #pragma unroll
        for (int f = 0; f < 3; ++f)
          #pragma unroll
          for (int r = 0; r < 4; ++r)
            Ru[(f * 16 + l16) * 40 + rr * 16 + quad * 4 + r] = f2b(acc[rr][f][r]);
      LFENCE();
      #pragma unroll
      for (int it = 0; it < 3; ++it) {
        int id = it * 64 + lane;
        int d = id >> 2, seg = id & 3;
        uint4 v = *(const uint4*)(Ru + d * 40 + seg * 8);
        *(uint4*)(vT + ((long)(h * KQK + n * 48 + d)) * LQ + i2base + w * 32 + seg * 8) = v;
      }
    } else {
      // gate: bf16 C into slice (stride 56), sigmoid(+bg), packed store
      u16* Ru = (u16*)R;
      #pragma unroll
      for (int rr = 0; rr < 2; ++rr)
        #pragma unroll
        for (int f = 0; f < 3; ++f)
          #pragma unroll
          for (int r = 0; r < 4; ++r)
            Ru[(rr * 16 + quad * 4 + r) * 56 + f * 16 + l16] = f2b(acc[rr][f][r]);
      LFENCE();
      u16* dst = gate3 + ((long)h * NPOS + pbase + w * 32 + row) * 48 + half * 24;
      #pragma unroll
      for (int v3 = 0; v3 < 3; ++v3) {
        union { u16 s[8]; uint4 q; } iv, o;
        iv.q = *(const uint4*)(Ru + row * 56 + half * 24 + v3 * 8);
        #pragma unroll
        for (int j = 0; j < 8; ++j) {
          float x = b2f(iv.s[j]) + bg[h * 48 + half * 24 + v3 * 8 + j];
          o.s[j] = f2b(1.f / (1.f + __expf(-x)));
        }
        *(uint4*)(dst + v3 * 8) = o.q;
      }
    }
  }
}

// ---------------- kernel 4: partial[s] = Q K^T slice, plane BK=96 (2 n-planes/kt)
// grid x = s*2+nt (32), y = mt(3), z = h(4); s covers 24 n-planes (12 kt)
__global__ __launch_bounds__(256) void k_qk(
    const u16* __restrict__ q48, const u16* __restrict__ k48,
    float* __restrict__ partial)
{
  __shared__ __align__(16) u16 sA[128 * 104];
  __shared__ __align__(16) u16 sB[192 * 104];
  int nt = blockIdx.x & 1, s = blockIdx.x >> 1;
  int mt = blockIdx.y, h = blockIdx.z;
  const int t = threadIdx.x;
  const int w = t >> 6, lane = t & 63, quad = lane >> 4, l16 = lane & 15;
  const int wr = w >> 1, wc = w & 1;
  f32x4 acc[4][6] = {};
  for (int kt = 0; kt < 12; ++kt) {
    int n0 = s * 24 + kt * 2;
    #pragma unroll
    for (int r = 0; r < 6; ++r) {           // A: 128 rows x 96 (2 planes x 48)
      int p = r / 3;
      int rem = t + (r - p * 3) * 256;
      int row = rem / 6, c8 = (rem % 6) * 8;
      *(uint4*)(sA + row * 104 + p * 48 + c8) =
        *(const uint4*)(q48 + (((long)h * LQ + n0 + p) * LQ + mt * 128 + row) * DH + c8);
    }
    #pragma unroll
    for (int r = 0; r < 9; ++r) {           // B: 192 rows x 96
      int id = t + r * 256;
      int p = (id >= 1152) ? 1 : 0;
      int rem = id - p * 1152;
      int row = rem / 6, c8 = (rem % 6) * 8;
      *(uint4*)(sB + row * 104 + p * 48 + c8) =
        *(const uint4*)(k48 + (((long)h * LQ + n0 + p) * LQ + nt * 192 + row) * DH + c8);
    }
    __syncthreads();
    #pragma unroll
    for (int kk = 0; kk < 96; kk += 32) {
      short8 a[4], bf[6];
      #pragma unroll
      for (int rr = 0; rr < 4; ++rr)
        a[rr] = *(const short8*)(sA + (wr * 64 + rr * 16 + l16) * 104 + kk + quad * 8);
      #pragma unroll
      for (int f = 0; f < 6; ++f)
        bf[f] = *(const short8*)(sB + (wc * 96 + f * 16 + l16) * 104 + kk + quad * 8);
      #pragma unroll
      for (int rr = 0; rr < 4; ++rr)
        #pragma unroll
        for (int f = 0; f < 6; ++f)
          acc[rr][f] = __builtin_amdgcn_mfma_f32_16x16x32_bf16(a[rr], bf[f], acc[rr][f], 0, 0, 0);
    }
    __syncthreads();
  }
  float* dst = partial + ((long)s * NH + h) * NPOS;
  #pragma unroll
  for (int rr = 0; rr < 4; ++rr)
    #pragma unroll
    for (int f = 0; f < 6; ++f)
      #pragma unroll
      for (int r = 0; r < 4; ++r) {
        int rowc = mt * 128 + wr * 64 + rr * 16 + quad * 4 + r;
        int col = nt * 192 + wc * 96 + f * 16 + l16;
        dst[(long)rowc * LQ + col] = acc[rr][f][r];
      }
}

// ---------------- kernel 5: reduce 16 partials + bh, softmax over j, mask -> attn
__global__ __launch_bounds__(256) void k_softmax(
    const float* __restrict__ partial, const float* __restrict__ bh,
    const float* __restrict__ mask, u16* __restrict__ attn)
{
  int w = threadIdx.x >> 6, lane = threadIdx.x & 63;
  long row = (long)blockIdx.x * 4 + w;   // row = h*384 + i
  int i = (int)(row % LQ);
  float v[6];
  #pragma unroll
  for (int j0 = 0; j0 < 6; ++j0) v[j0] = bh[row * LQ + lane + j0 * 64];
  for (int s = 0; s < 16; ++s) {
    const float* p = partial + (long)s * NH * NPOS + row * LQ;
    #pragma unroll
    for (int j0 = 0; j0 < 6; ++j0) v[j0] += p[lane + j0 * 64];
  }
  float mx = -1e30f;
  #pragma unroll
  for (int j0 = 0; j0 < 6; ++j0) mx = fmaxf(mx, v[j0]);
  #pragma unroll
  for (int o = 32; o; o >>= 1) mx = fmaxf(mx, __shfl_down(mx, o));
  mx = __shfl(mx, 0);
  float sum = 0.f;
  #pragma unroll
  for (int j0 = 0; j0 < 6; ++j0) { v[j0] = __expf(v[j0] - mx); sum += v[j0]; }
  sum = wred_sum(sum);
  float inv = 1.f / sum;
  #pragma unroll
  for (int j0 = 0; j0 < 6; ++j0) {
    int j = lane + j0 * 64;
    float p = v[j0] * inv + 1.0e6f * (mask[(long)i * LQ + j] - 1.f);
    attn[row * LQ + j] = f2b(p);
  }
}

// ---------------- kernel 6: out3[h][n][i][48] = attn @ vT^T, per-wave repack. grid (96, 4)
__global__ __launch_bounds__(256) void k_av(
    const u16* __restrict__ attn, const u16* __restrict__ vT,
    u16* __restrict__ out3)
{
  __shared__ __align__(16) u16 sA[128 * 72];    // 18432 B (also repack slices)
  __shared__ __align__(16) u16 sB[192 * 72];    // 27648 B
  int nt = blockIdx.x, h = blockIdx.y;
  const int t = threadIdx.x;
  const int w = t >> 6, lane = t & 63, quad = lane >> 4, l16 = lane & 15;
  const int wr = w >> 1, wc = w & 1;
  const int plane = lane >> 5, row16 = (lane >> 1) & 15, half = lane & 1;
  for (int mt = 0; mt < 3; ++mt) {
    f32x4 acc[4][6] = {};
    gemm_128x192(attn + ((long)h * LQ + mt * 128) * LQ, LQ,
                 vT + ((long)h * KQK + nt * 192) * LQ, LQ,
                 6, sA, sB, acc);
    // per-wave repack via sA slice (gemm's trailing barrier freed sA; no stores pending there)
    u16* R = (u16*)((char*)sA + w * 4608);
    #pragma unroll
    for (int rr = 0; rr < 4; ++rr) {
      LFENCE();
      #pragma unroll
      for (int f = 0; f < 6; ++f)
        #pragma unroll
        for (int r = 0; r < 4; ++r)
          R[(quad * 4 + r) * 104 + f * 16 + l16] = f2b(acc[rr][f][r]);
      LFENCE();
      int nn = nt * 4 + wc * 2 + plane;
      int i = mt * 128 + wr * 64 + rr * 16 + row16;
      const u16* src = R + row16 * 104 + plane * 48 + half * 24;
      u16* dst = out3 + ((long)h * NPOS + (long)nn * LQ + i) * 48 + half * 24;
      *(uint4*)(dst)      = *(const uint4*)(src);
      *(uint4*)(dst + 8)  = *(const uint4*)(src + 8);
      *(uint4*)(dst + 16) = *(const uint4*)(src + 16);
    }
    if (mt != 2) __syncthreads();   // protect sA before next staging (stores already ~1 chunk old)
  }
}

// ---------------- kernel 7: final = (out3 .* gate3) @ Wo, per-wave repacked fp32 stores
__global__ __launch_bounds__(256) void k_out(
    const u16* __restrict__ out3, const u16* __restrict__ gate3,
    const u16* __restrict__ WoT, float* __restrict__ outp)
{
  __shared__ __align__(16) u16 sA[128 * 104];   // 26624 B
  __shared__ __align__(16) u16 sB[128 * 104];   // 26624 B (repack slices after MFMA)
  long mt = blockIdx.x;
  long pbase = mt * 128;
  const int t = threadIdx.x;
  const int w = t >> 6, lane = t & 63, quad = lane >> 4, l16 = lane & 15;
  const int wr = w >> 1, wc = w & 1;
  f32x4 acc[4][4] = {};
  for (int kt = 0; kt < 2; ++kt) {
    #pragma unroll
    for (int r = 0; r < 6; ++r) {      // A: 128 x 96 = planes (kt*2, kt*2+1), gate fused
      int p = r / 3;
      int rem = t + (r - p * 3) * 256;
      int row = rem / 6, c8 = (rem % 6) * 8;
      long off = ((long)(kt * 2 + p) * NPOS + pbase + row) * DH + c8;
      union { u16 s[8]; uint4 v; } ua, ub, ur;
      ua.v = *(const uint4*)(out3 + off);
      ub.v = *(const uint4*)(gate3 + off);
      #pragma unroll
      for (int q2 = 0; q2 < 8; ++q2) ur.s[q2] = f2b(b2f(ua.s[q2]) * b2f(ub.s[q2]));
      *(uint4*)(sA + row * 104 + p * 48 + c8) = ur.v;
    }
    #pragma unroll
    for (int r = 0; r < 6; ++r) {      // B: 128 rows(c) x 96 K
      int p = r / 3;
      int rem = t + (r - p * 3) * 256;
      int row = rem / 6, c8 = (rem % 6) * 8;
      *(uint4*)(sB + row * 104 + p * 48 + c8) =
        *(const uint4*)(WoT + (long)row * 192 + kt * 96 + p * 48 + c8);
    }
    __syncthreads();
    #pragma unroll
    for (int kk = 0; kk < 96; kk += 32) {
      short8 a[4], bf[4];
      #pragma unroll
      for (int rr = 0; rr < 4; ++rr)
        a[rr] = *(const short8*)(sA + (wr * 64 + rr * 16 + l16) * 104 + kk + quad * 8);
      #pragma unroll
      for (int f = 0; f < 4; ++f)
        bf[f] = *(const short8*)(sB + (wc * 64 + f * 16 + l16) * 104 + kk + quad * 8);
      #pragma unroll
      for (int rr = 0; rr < 4; ++rr)
        #pragma unroll
        for (int f = 0; f < 4; ++f)
          acc[rr][f] = __builtin_amdgcn_mfma_f32_16x16x32_bf16(a[rr], bf[f], acc[rr][f], 0, 0, 0);
    }
    __syncthreads();
  }
  int n = (int)(pbase / LQ), ibase = (int)(pbase % LQ);
  // per-wave fp32 repack via sB slices (last barrier freed sB; no stores pending)
  float* R = (float*)((char*)sB + w * 6656);
  const int row16 = lane >> 2, q4 = lane & 3;
  #pragma unroll
  for (int rr = 0; rr < 4; ++rr) {
    LFENCE();
    #pragma unroll
    for (int f = 0; f < 4; ++f)
      #pragma unroll
      for (int r = 0; r < 4; ++r)
        R[(quad * 4 + r) * 68 + f * 16 + l16] = acc[rr][f][r];
    LFENCE();
    int i = ibase + wr * 64 + rr * 16 + row16;
    float* dst = outp + ((long)i * LQ + n) * DE + wc * 64 + q4 * 16;
    const float* src = R + row16 * 68 + q4 * 16;
    #pragma unroll
    for (int v = 0; v < 4; ++v)
      *(float4*)(dst + v * 4) = *(const float4*)(src + v * 4);
  }
}

extern "C" void kernel_launch(void* const* d_in, const int* in_sizes, int n_in,
                              void* d_out, int out_size, void* d_ws, size_t ws_size,
                              hipStream_t stream)
{
  const float* edge   = (const float*)d_in[0];
  const float* bias   = (const float*)d_in[1];
  const int*   epos   = (const int*)d_in[2];
  const float* mask   = (const float*)d_in[3];
  const float* ln_e_g = (const float*)d_in[4];
  const float* ln_e_b = (const float*)d_in[5];
  const float* ln_b_g = (const float*)d_in[6];
  const float* ln_b_b = (const float*)d_in[7];
  const float* Wq = (const float*)d_in[8];
  const float* Wk = (const float*)d_in[9];
  const float* Wv = (const float*)d_in[10];
  const float* Wb = (const float*)d_in[11];
  const float* Wg = (const float*)d_in[12];
  const float* bg = (const float*)d_in[13];
  const float* Wo = (const float*)d_in[14];
  float* outp = (float*)d_out;

  char* ws = (char*)d_ws;
  const size_t SZ = (size_t)NPOS * 192 * 2;   // 56,623,104 B
  // slot0 timeline: e_ln (k_ln_e->k_proj) -> partial (k_qk->k_softmax) -> out3 (k_av->k_out)
  u16* e_ln      = (u16*)ws;                  // 37.7 MB
  float* partial = (float*)ws;                // 16 x 2.36 MB = 37.7 MB
  u16* out3      = (u16*)ws;                  // [4][147456][48] = 56.6 MB
  u16* q48   = (u16*)(ws + SZ);               // [4][384][384][48]
  u16* k48   = (u16*)(ws + 2 * SZ);
  u16* vTb   = (u16*)(ws + 3 * SZ);
  u16* gate3 = (u16*)(ws + 4 * SZ);           // [4][147456][48]
  float* bh  = (float*)(ws + 5 * SZ);         // [4][384][384] fp32
  u16* attn  = (u16*)(ws + 5 * SZ + 2359296);
  u16* WT    = (u16*)(ws + 5 * SZ + 2359296 + 1179648);
  u16* WoT   = (u16*)(ws + 5 * SZ + 2359296 + 1179648 + 196608);
  float* cosT = (float*)(ws + 5 * SZ + 2359296 + 1179648 + 196608 + 49152);
  float* sinT = cosT + 384 * 24;

  k_prep_w<<<dim3(384), dim3(256), 0, stream>>>(Wq, Wk, Wv, Wg, Wo, epos, WT, WoT, cosT, sinT);
  k_bias<<<dim3(36864), dim3(256), 0, stream>>>(bias, ln_b_g, ln_b_b, Wb, bh);
  k_ln_e<<<dim3(36864), dim3(256), 0, stream>>>(edge, ln_e_g, ln_e_b, e_ln);
  k_proj<<<dim3(1152), dim3(256), 0, stream>>>(e_ln, WT, cosT, sinT, bg,
                                               q48, k48, vTb, gate3);
  k_qk<<<dim3(32, 3, 4), dim3(256), 0, stream>>>(q48, k48, partial);
  k_softmax<<<dim3(384), dim3(256), 0, stream>>>(partial, bh, mask, attn);
  k_av<<<dim3(96, 4), dim3(256), 0, stream>>>(attn, vTb, out3);
  k_out<<<dim3(1152), dim3(256), 0, stream>>>(out3, gate3, WoT, outp);
}